// Round 4
// baseline (49013.062 us; speedup 1.0000x reference)
//
#include <hip/hip_runtime.h>
#include <math.h>

#define T_STEPS 8192
#define HID 2048
#define H3 6144
#define NBLK 256
#define CHUNK 2048

// ---------------------------------------------------------------------------
// Coherent (cross-XCD) access helpers: sc0 sc1 bypass L1/L2 to the
// Infinity-Cache coherence point. No cache maintenance (wbl2/inv) needed.
// Empirically validated (R3): drain(vmcnt0) -> flag handoff is coherent.
// ---------------------------------------------------------------------------
__device__ __forceinline__ float4 cload_f4(const float* p) {
    float4 r;
    asm volatile("global_load_dwordx4 %0, %1, off sc0 sc1\n\t"
                 "s_waitcnt vmcnt(0)"
                 : "=&v"(r) : "v"(p) : "memory");
    return r;
}
__device__ __forceinline__ void cstore_f1(float* p, float v) {
    asm volatile("global_store_dword %0, %1, off sc0 sc1"
                 :: "v"(p), "v"(v) : "memory");
}
__device__ __forceinline__ void drain_stores() {
    asm volatile("s_waitcnt vmcnt(0)" ::: "memory");
}

// ---------------------------------------------------------------------------
// fp32 GEMM: C[M,N] = A[M,K] @ B[N,K]^T + bias, optional ReLU.
// 64x64 tile, TK=16, 256 threads, 4x4 per thread. M%64==0, K%16==0; N guarded.
// ---------------------------------------------------------------------------
template<int RELU>
__global__ __launch_bounds__(256) void sgemm_bias(
    const float* __restrict__ A, const float* __restrict__ B,
    const float* __restrict__ bias, float* __restrict__ C,
    int M, int N, int K)
{
    __shared__ float As[16][64];
    __shared__ float Bs[16][64];
    const int tid = threadIdx.x;
    const int tm = tid & 15;
    const int tn = tid >> 4;
    const int m0 = blockIdx.y * 64;
    const int n0 = blockIdx.x * 64;
    const int lm = tid >> 2;        // 0..63 row within tile
    const int lk = (tid & 3) * 4;   // 0,4,8,12

    float c[4][4] = {};

    for (int k0 = 0; k0 < K; k0 += 16) {
        float4 av = *(const float4*)(A + (size_t)(m0 + lm) * K + k0 + lk);
        float4 bv = make_float4(0.f, 0.f, 0.f, 0.f);
        const int bn = n0 + lm;
        if (bn < N) bv = *(const float4*)(B + (size_t)bn * K + k0 + lk);
        __syncthreads();
        As[lk+0][lm] = av.x; As[lk+1][lm] = av.y; As[lk+2][lm] = av.z; As[lk+3][lm] = av.w;
        Bs[lk+0][lm] = bv.x; Bs[lk+1][lm] = bv.y; Bs[lk+2][lm] = bv.z; Bs[lk+3][lm] = bv.w;
        __syncthreads();
        #pragma unroll
        for (int kk = 0; kk < 16; kk++) {
            float4 a4 = *(const float4*)&As[kk][tm * 4];
            float4 b4 = *(const float4*)&Bs[kk][tn * 4];
            c[0][0] += a4.x * b4.x; c[0][1] += a4.x * b4.y; c[0][2] += a4.x * b4.z; c[0][3] += a4.x * b4.w;
            c[1][0] += a4.y * b4.x; c[1][1] += a4.y * b4.y; c[1][2] += a4.y * b4.z; c[1][3] += a4.y * b4.w;
            c[2][0] += a4.z * b4.x; c[2][1] += a4.z * b4.y; c[2][2] += a4.z * b4.z; c[2][3] += a4.z * b4.w;
            c[3][0] += a4.w * b4.x; c[3][1] += a4.w * b4.y; c[3][2] += a4.w * b4.z; c[3][3] += a4.w * b4.w;
        }
    }

    const int mrow = m0 + tm * 4;
    #pragma unroll
    for (int i = 0; i < 4; i++) {
        #pragma unroll
        for (int j = 0; j < 4; j++) {
            const int n = n0 + tn * 4 + j;
            if (n < N) {
                float v = c[i][j] + bias[n];
                if (RELU) v = fmaxf(v, 0.f);
                C[(size_t)(mrow + i) * N + n] = v;
            }
        }
    }
}

// ---------------------------------------------------------------------------
// fp32 GEMM (B not transposed): C[M,N] = A[M,K] @ B[K,N]. No bias.
// Used once: W_comb[6144,64] = w_ih[6144,2048] @ enc_w[2048,64].
// ---------------------------------------------------------------------------
__global__ __launch_bounds__(256) void sgemm_nn(
    const float* __restrict__ A, const float* __restrict__ B,
    float* __restrict__ C, int M, int N, int K)
{
    __shared__ float As[16][64];
    __shared__ float Bs[16][64];
    const int tid = threadIdx.x;
    const int tm = tid & 15;
    const int tn = tid >> 4;
    const int m0 = blockIdx.y * 64;
    const int n0 = blockIdx.x * 64;
    const int lm = tid >> 2;
    const int lk = (tid & 3) * 4;
    const int bk  = tid >> 4;         // 0..15
    const int bn4 = (tid & 15) * 4;   // 0..60

    float c[4][4] = {};

    for (int k0 = 0; k0 < K; k0 += 16) {
        float4 av = *(const float4*)(A + (size_t)(m0 + lm) * K + k0 + lk);
        float4 bv = *(const float4*)(B + (size_t)(k0 + bk) * N + n0 + bn4);
        __syncthreads();
        As[lk+0][lm] = av.x; As[lk+1][lm] = av.y; As[lk+2][lm] = av.z; As[lk+3][lm] = av.w;
        *(float4*)&Bs[bk][bn4] = bv;
        __syncthreads();
        #pragma unroll
        for (int kk = 0; kk < 16; kk++) {
            float4 a4 = *(const float4*)&As[kk][tm * 4];
            float4 b4 = *(const float4*)&Bs[kk][tn * 4];
            c[0][0] += a4.x * b4.x; c[0][1] += a4.x * b4.y; c[0][2] += a4.x * b4.z; c[0][3] += a4.x * b4.w;
            c[1][0] += a4.y * b4.x; c[1][1] += a4.y * b4.y; c[1][2] += a4.y * b4.z; c[1][3] += a4.y * b4.w;
            c[2][0] += a4.z * b4.x; c[2][1] += a4.z * b4.y; c[2][2] += a4.z * b4.z; c[2][3] += a4.z * b4.w;
            c[3][0] += a4.w * b4.x; c[3][1] += a4.w * b4.y; c[3][2] += a4.w * b4.z; c[3][3] += a4.w * b4.w;
        }
    }

    const int mrow = m0 + tm * 4;
    #pragma unroll
    for (int i = 0; i < 4; i++) {
        #pragma unroll
        for (int j = 0; j < 4; j++)
            C[(size_t)(mrow + i) * N + n0 + tn * 4 + j] = c[i][j];
    }
}

// ---------------------------------------------------------------------------
// b_comb[r] = dot(w_ih[r,:], enc_b) + b_ih[r].  One wave per row.
// ---------------------------------------------------------------------------
__global__ __launch_bounds__(256) void bcomb_kernel(
    const float* __restrict__ w_ih, const float* __restrict__ enc_b,
    const float* __restrict__ b_ih, float* __restrict__ b_comb)
{
    const int wv = threadIdx.x >> 6, lane = threadIdx.x & 63;
    const int r = blockIdx.x * 4 + wv;
    const float* row = w_ih + (size_t)r * HID;
    float acc = 0.f;
    for (int j = lane; j < HID; j += 64) acc += row[j] * enc_b[j];
    #pragma unroll
    for (int m = 32; m >= 1; m >>= 1) acc += __shfl_xor(acc, m, 64);
    if (lane == 0) b_comb[r] = acc + b_ih[r];
}

// ---------------------------------------------------------------------------
// Persistent GRU scan over `steps` steps. 256 blocks x 512 threads, 1 blk/CU.
// Block b owns h[b*8 .. b*8+7] -> 24 rows of w_hh in registers.
// RMW-FREE barrier: block b stores flags[b]=stamp (sc1, after h-store drain);
// wave 0 of every block polls ALL 256 flags with one dwordx4/lane (1KB) and
// ballots. No atomics, no fences, monotonic stamps across chunk launches.
// ---------------------------------------------------------------------------
__global__ __launch_bounds__(512, 2) void gru_scan(
    const float* __restrict__ w_hh, const float* __restrict__ b_n,
    const float* __restrict__ ig,   // [steps,3,H] fp32 for this chunk
    float* __restrict__ hs,         // [steps,H] output states (chunk base)
    float* __restrict__ hbuf,      // 2*H ping-pong, h in parity 0 at entry
    float* __restrict__ flags,      // NBLK stamps, zeroed at launch
    int base, int steps)
{
    __shared__ float h_lds[HID];
    __shared__ float hg_lds[24];
    const int tid  = threadIdx.x;
    const int lane = tid & 63;
    const int w    = tid >> 6;
    const int b    = blockIdx.x;

    // ---- 96 weights per thread into registers (coalesced) ----
    float4 wreg[3][8];
    #pragma unroll
    for (int q = 0; q < 3; q++) {
        const int idx3 = w * 3 + q;                     // 0..23
        const int row  = (idx3 >> 3) * HID + b * 8 + (idx3 & 7);
        const float4* wp = (const float4*)(w_hh + (size_t)row * HID);
        #pragma unroll
        for (int v = 0; v < 8; v++) wreg[q][v] = wp[v * 64 + lane];
    }

    const int i = b * 8 + tid;      // global h index (valid for tid<8)
    float h_own = 0.f, bn = 0.f, ign0 = 0.f, ign1 = 0.f, ign2 = 0.f;
    if (tid < 8) {
        bn   = b_n[i];
        h_own = hbuf[i];            // kernel-boundary visibility: plain load ok
        ign0 = ig[i]; ign1 = ig[HID + i]; ign2 = ig[2 * HID + i];
    }

    for (int t = 0; t < steps; t++) {
        const float* cur = hbuf + (t & 1) * HID;
        float*       nxt = hbuf + ((t + 1) & 1) * HID;

        // stage h into LDS via coherent load (512 threads x float4 = 8KB)
        float4 hv4 = cload_f4(cur + tid * 4);
        *(float4*)&h_lds[tid * 4] = hv4;

        const float ig0 = ign0, ig1 = ign1, ig2 = ign2;
        if (tid < 8 && t + 1 < steps) {        // prefetch next step's gates
            const float* p = ig + (size_t)(t + 1) * H3 + i;
            ign0 = p[0]; ign1 = p[HID]; ign2 = p[2 * HID];
        }
        __syncthreads();

        // ---- 3 dots of length 2048: 32 elems/lane, regs x LDS ----
        float acc0 = 0.f, acc1 = 0.f, acc2 = 0.f;
        #pragma unroll
        for (int v = 0; v < 8; v++) {
            float4 hv = *(const float4*)&h_lds[v * 256 + lane * 4];
            acc0 += wreg[0][v].x * hv.x + wreg[0][v].y * hv.y + wreg[0][v].z * hv.z + wreg[0][v].w * hv.w;
            acc1 += wreg[1][v].x * hv.x + wreg[1][v].y * hv.y + wreg[1][v].z * hv.z + wreg[1][v].w * hv.w;
            acc2 += wreg[2][v].x * hv.x + wreg[2][v].y * hv.y + wreg[2][v].z * hv.z + wreg[2][v].w * hv.w;
        }
        #pragma unroll
        for (int m = 32; m >= 1; m >>= 1) {
            acc0 += __shfl_xor(acc0, m, 64);
            acc1 += __shfl_xor(acc1, m, 64);
            acc2 += __shfl_xor(acc2, m, 64);
        }
        if (lane == 0) {
            hg_lds[w * 3 + 0] = acc0;
            hg_lds[w * 3 + 1] = acc1;
            hg_lds[w * 3 + 2] = acc2;
        }
        __syncthreads();

        // ---- gates + state update (8 threads, all in wave 0) ----
        if (tid < 8) {
            const float r = 1.f / (1.f + expf(-(ig0 + hg_lds[tid])));
            const float z = 1.f / (1.f + expf(-(ig1 + hg_lds[8 + tid])));
            const float n = tanhf(ig2 + r * (hg_lds[16 + tid] + bn));
            h_own = n + z * (h_own - n);
            cstore_f1(nxt + i, h_own);         // coherent store (IC)
            hs[(size_t)t * HID + i] = h_own;   // plain cached store
        }

        // ---- RMW-free grid barrier (wave 0 only) ----
        const float stamp = (float)(base + t + 1);   // exact in fp32 (<2^23)
        if (w == 0) {
            drain_stores();                    // wave-0's h stores -> at IC
            if (lane == 0) cstore_f1(flags + b, stamp);
            const float* fp = flags + lane * 4;      // 64 lanes x 4 = all 256
            for (;;) {
                float4 f = cload_f4(fp);
                const bool ok = (f.x >= stamp) & (f.y >= stamp) &
                                (f.z >= stamp) & (f.w >= stamp);
                if (__ballot(ok) == ~0ull) break;
            }
        }
        __syncthreads();
    }
}

// ---------------------------------------------------------------------------
extern "C" void kernel_launch(void* const* d_in, const int* in_sizes, int n_in,
                              void* d_out, int out_size, void* d_ws, size_t ws_size,
                              hipStream_t stream) {
    const float* x     = (const float*)d_in[0];
    const float* enc_w = (const float*)d_in[1];
    const float* enc_b = (const float*)d_in[2];
    const float* w_ih  = (const float*)d_in[3];
    const float* w_hh  = (const float*)d_in[4];
    const float* b_ih  = (const float*)d_in[5];
    const float* b_n   = (const float*)d_in[6];
    const float* w0    = (const float*)d_in[7];
    const float* b0    = (const float*)d_in[8];
    const float* w1    = (const float*)d_in[9];
    const float* b1    = (const float*)d_in[10];
    const float* w2    = (const float*)d_in[11];
    const float* b2    = (const float*)d_in[12];
    float* out = (float*)d_out;

    // workspace (~136 MB): R1 64MB (ig chunk -> dec h1), R2 64MB (hs -> dec h2)
    float* R1    = (float*)d_ws;                          // 16,777,216 f
    float* R2    = R1 + (size_t)16777216;                 // 16,777,216 f
    float* wcomb = R2 + (size_t)16777216;                 // 393,216 f
    float* bcomb = wcomb + 393216;                        // 6,144 f
    float* hbuf  = bcomb + 6144;                          // 4,096 f
    float* flags = hbuf + 4096;                           // 256 f

    hipMemsetAsync(hbuf, 0, (4096 + NBLK) * sizeof(float), stream);

    // fold encoder into GRU input weights:
    //   W_comb = w_ih @ enc_w   [6144,64];  b_comb = w_ih @ enc_b + b_ih
    sgemm_nn<<<dim3(1, 96), 256, 0, stream>>>(w_ih, enc_w, wcomb, 6144, 64, 2048);
    bcomb_kernel<<<dim3(1536), 256, 0, stream>>>(w_ih, enc_b, b_ih, bcomb);

    // chunked: ig = x @ W_comb^T + b_comb (K=64), then sequential scan
    for (int c = 0; c < T_STEPS / CHUNK; c++) {
        sgemm_bias<0><<<dim3(H3 / 64, CHUNK / 64), 256, 0, stream>>>(
            x + (size_t)c * CHUNK * 64, wcomb, bcomb, R1, CHUNK, H3, 64);
        gru_scan<<<dim3(NBLK), dim3(512), 0, stream>>>(
            w_hh, b_n, R1, R2 + (size_t)c * CHUNK * HID, hbuf, flags, c * CHUNK, CHUNK);
    }

    // decoder MLP (aliased: R2=hs -> R1=h1 -> R2=h2 -> out)
    sgemm_bias<1><<<dim3(HID / 64, T_STEPS / 64), 256, 0, stream>>>(
        R2, w0, b0, R1, T_STEPS, HID, HID);
    sgemm_bias<1><<<dim3(HID / 64, T_STEPS / 64), 256, 0, stream>>>(
        R1, w1, b1, R2, T_STEPS, HID, HID);
    sgemm_bias<0><<<dim3(1, T_STEPS / 64), 256, 0, stream>>>(
        R2, w2, b2, out, T_STEPS, 49, 2048);
}

// Round 6
// 27274.335 us; speedup vs baseline: 1.7970x; 1.7970x over previous
//
#include <hip/hip_runtime.h>
#include <math.h>

#define T_STEPS 8192
#define HID 2048
#define H3 6144
#define NBLK 256
#define CHUNK 2048

typedef float f32x4 __attribute__((ext_vector_type(4)));

// ---------------------------------------------------------------------------
// Coherent (cross-XCD) access: sc0 sc1 bypasses L1/L2 to the Infinity-Cache
// coherence point. Empirically validated (R3/R4) for producer/consumer h
// exchange. A single 16B dwordx4 store lands as one IC transaction.
// NOTE: inline-asm INPUTS must be ext_vector_type, not the float4 struct
// (LLVM: "indirect register inputs" error). Outputs accept float4.
// ---------------------------------------------------------------------------
__device__ __forceinline__ float4 cload_f4(const float* p) {
    float4 r;
    asm volatile("global_load_dwordx4 %0, %1, off sc0 sc1\n\t"
                 "s_waitcnt vmcnt(0)"
                 : "=&v"(r) : "v"(p) : "memory");
    return r;
}
__device__ __forceinline__ void cstore_f4(float4* p, float x, float y,
                                          float z, float w) {
    f32x4 v; v[0] = x; v[1] = y; v[2] = z; v[3] = w;
    asm volatile("global_store_dwordx4 %0, %1, off sc0 sc1"
                 :: "v"(p), "v"(v) : "memory");
}

// ---------------------------------------------------------------------------
// fp32 GEMM: C[M,N] = A[M,K] @ B[N,K]^T + bias, optional ReLU.
// ---------------------------------------------------------------------------
template<int RELU>
__global__ __launch_bounds__(256) void sgemm_bias(
    const float* __restrict__ A, const float* __restrict__ B,
    const float* __restrict__ bias, float* __restrict__ C,
    int M, int N, int K)
{
    __shared__ float As[16][64];
    __shared__ float Bs[16][64];
    const int tid = threadIdx.x;
    const int tm = tid & 15;
    const int tn = tid >> 4;
    const int m0 = blockIdx.y * 64;
    const int n0 = blockIdx.x * 64;
    const int lm = tid >> 2;
    const int lk = (tid & 3) * 4;

    float c[4][4] = {};

    for (int k0 = 0; k0 < K; k0 += 16) {
        float4 av = *(const float4*)(A + (size_t)(m0 + lm) * K + k0 + lk);
        float4 bv = make_float4(0.f, 0.f, 0.f, 0.f);
        const int bn = n0 + lm;
        if (bn < N) bv = *(const float4*)(B + (size_t)bn * K + k0 + lk);
        __syncthreads();
        As[lk+0][lm] = av.x; As[lk+1][lm] = av.y; As[lk+2][lm] = av.z; As[lk+3][lm] = av.w;
        Bs[lk+0][lm] = bv.x; Bs[lk+1][lm] = bv.y; Bs[lk+2][lm] = bv.z; Bs[lk+3][lm] = bv.w;
        __syncthreads();
        #pragma unroll
        for (int kk = 0; kk < 16; kk++) {
            float4 a4 = *(const float4*)&As[kk][tm * 4];
            float4 b4 = *(const float4*)&Bs[kk][tn * 4];
            c[0][0] += a4.x * b4.x; c[0][1] += a4.x * b4.y; c[0][2] += a4.x * b4.z; c[0][3] += a4.x * b4.w;
            c[1][0] += a4.y * b4.x; c[1][1] += a4.y * b4.y; c[1][2] += a4.y * b4.z; c[1][3] += a4.y * b4.w;
            c[2][0] += a4.z * b4.x; c[2][1] += a4.z * b4.y; c[2][2] += a4.z * b4.z; c[2][3] += a4.z * b4.w;
            c[3][0] += a4.w * b4.x; c[3][1] += a4.w * b4.y; c[3][2] += a4.w * b4.z; c[3][3] += a4.w * b4.w;
        }
    }

    const int mrow = m0 + tm * 4;
    #pragma unroll
    for (int i = 0; i < 4; i++) {
        #pragma unroll
        for (int j = 0; j < 4; j++) {
            const int n = n0 + tn * 4 + j;
            if (n < N) {
                float v = c[i][j] + bias[n];
                if (RELU) v = fmaxf(v, 0.f);
                C[(size_t)(mrow + i) * N + n] = v;
            }
        }
    }
}

// ---------------------------------------------------------------------------
// fp32 GEMM (B not transposed): C[M,N] = A[M,K] @ B[K,N]. No bias.
// Used once: W_comb[6144,64] = w_ih[6144,2048] @ enc_w[2048,64].
// ---------------------------------------------------------------------------
__global__ __launch_bounds__(256) void sgemm_nn(
    const float* __restrict__ A, const float* __restrict__ B,
    float* __restrict__ C, int M, int N, int K)
{
    __shared__ float As[16][64];
    __shared__ float Bs[16][64];
    const int tid = threadIdx.x;
    const int tm = tid & 15;
    const int tn = tid >> 4;
    const int m0 = blockIdx.y * 64;
    const int n0 = blockIdx.x * 64;
    const int lm = tid >> 2;
    const int lk = (tid & 3) * 4;
    const int bk  = tid >> 4;
    const int bn4 = (tid & 15) * 4;

    float c[4][4] = {};

    for (int k0 = 0; k0 < K; k0 += 16) {
        float4 av = *(const float4*)(A + (size_t)(m0 + lm) * K + k0 + lk);
        float4 bv = *(const float4*)(B + (size_t)(k0 + bk) * N + n0 + bn4);
        __syncthreads();
        As[lk+0][lm] = av.x; As[lk+1][lm] = av.y; As[lk+2][lm] = av.z; As[lk+3][lm] = av.w;
        *(float4*)&Bs[bk][bn4] = bv;
        __syncthreads();
        #pragma unroll
        for (int kk = 0; kk < 16; kk++) {
            float4 a4 = *(const float4*)&As[kk][tm * 4];
            float4 b4 = *(const float4*)&Bs[kk][tn * 4];
            c[0][0] += a4.x * b4.x; c[0][1] += a4.x * b4.y; c[0][2] += a4.x * b4.z; c[0][3] += a4.x * b4.w;
            c[1][0] += a4.y * b4.x; c[1][1] += a4.y * b4.y; c[1][2] += a4.y * b4.z; c[1][3] += a4.y * b4.w;
            c[2][0] += a4.z * b4.x; c[2][1] += a4.z * b4.y; c[2][2] += a4.z * b4.z; c[2][3] += a4.z * b4.w;
            c[3][0] += a4.w * b4.x; c[3][1] += a4.w * b4.y; c[3][2] += a4.w * b4.z; c[3][3] += a4.w * b4.w;
        }
    }

    const int mrow = m0 + tm * 4;
    #pragma unroll
    for (int i = 0; i < 4; i++) {
        #pragma unroll
        for (int j = 0; j < 4; j++)
            C[(size_t)(mrow + i) * N + n0 + tn * 4 + j] = c[i][j];
    }
}

// ---------------------------------------------------------------------------
// b_comb[r] = dot(w_ih[r,:], enc_b) + b_ih[r].  One wave per row.
// ---------------------------------------------------------------------------
__global__ __launch_bounds__(256) void bcomb_kernel(
    const float* __restrict__ w_ih, const float* __restrict__ enc_b,
    const float* __restrict__ b_ih, float* __restrict__ b_comb)
{
    const int wv = threadIdx.x >> 6, lane = threadIdx.x & 63;
    const int r = blockIdx.x * 4 + wv;
    const float* row = w_ih + (size_t)r * HID;
    float acc = 0.f;
    for (int j = lane; j < HID; j += 64) acc += row[j] * enc_b[j];
    #pragma unroll
    for (int m = 32; m >= 1; m >>= 1) acc += __shfl_xor(acc, m, 64);
    if (lane == 0) b_comb[r] = acc + b_ih[r];
}

// ---------------------------------------------------------------------------
// Persistent GRU scan. 256 blocks x 1024 threads, 1 block/CU.
// Block b owns h[8b..8b+7] -> 24 rows of w_hh; wave-pair k (waves 2k,2k+1)
// owns rows idx3=3k..3k+2; thread holds 48 weight floats (12 float4) ->
// ~100 VGPR total, under the 128 cap of __launch_bounds__(1024,4), so the
// allocator keeps weights RESIDENT (R2-R4 failure: 96 floats vs chosen 72).
// Exchange: fused h+stamp atoms. Atom a = [h[2a], h[2a+1], stamp, pad]
// (16B, single IC transaction => data+stamp atomic). Producers (4 lanes of
// wave 0) fire one dwordx4 sc0sc1 store each; every thread polls ITS OWN
// atom - the successful poll already contains the data (1 IC round trip,
// no drain, no flag array). Self-atom gating orders intra-block reuse:
// threads 4b..4b+3 (writers of h_lds[8b..8b+8)) can't pass their poll until
// our own wave 0 publishes, which happens after it reads h_lds[8b+lane].
// ---------------------------------------------------------------------------
__global__ __launch_bounds__(1024, 4) void gru_scan(
    const float* __restrict__ w_hh, const float* __restrict__ b_n,
    const float* __restrict__ ig,   // [steps,3,H] fp32 for this chunk
    float* __restrict__ hs,         // [steps,H] output states (chunk base)
    float4* __restrict__ atoms,     // 2 x 1024 atoms, zeroed at launch
    int base, int steps)
{
    __shared__ float h_lds[HID];
    __shared__ float pg[16][3];
    __shared__ float hg_lds[24];
    const int tid  = threadIdx.x;
    const int lane = tid & 63;
    const int w    = tid >> 6;      // wave 0..15
    const int pr   = tid & 127;     // pair-local lane 0..127
    const int k    = tid >> 7;      // wave-pair 0..7
    const int b    = blockIdx.x;

    // ---- 48 weights per thread (12 float4), coalesced ----
    // rows idx3 = 3k+j ; cols 4*pr + 512*m (m=0..3)
    float4 wreg[3][4];
    #pragma unroll
    for (int j = 0; j < 3; j++) {
        const int idx3 = 3 * k + j;
        const float* wp = w_hh +
            (size_t)((idx3 >> 3) * HID + b * 8 + (idx3 & 7)) * HID;
        #pragma unroll
        for (int m = 0; m < 4; m++)
            wreg[j][m] = *(const float4*)(wp + 4 * pr + 512 * m);
    }

    const int i = b * 8 + tid;                 // valid for tid<8
    const float bn = (tid < 8) ? b_n[i] : 0.f;

    for (int t = 0; t < steps; t++) {
        // ig loads for this step (tid<8, wave 0) - in flight during poll
        float ig0 = 0.f, ig1 = 0.f, ig2 = 0.f;
        if (tid < 8) {
            const float* p = ig + (size_t)t * H3 + i;
            ig0 = p[0]; ig1 = p[HID]; ig2 = p[2 * HID];
        }

        // ---- poll own atom: one IC round trip returns stamp AND data ----
        const float target = (float)(base + t);          // exact in fp32
        const float* ap = (const float*)(atoms + (t & 1) * 1024 + tid);
        float4 f;
        do { f = cload_f4(ap); } while (f.z < target);
        *(float2*)&h_lds[2 * tid] = make_float2(f.x, f.y);
        __syncthreads();

        // ---- dot: rows 3k..3k+2, cols 4*pr+512m, weights in registers ----
        float a0 = 0.f, a1 = 0.f, a2 = 0.f;
        #pragma unroll
        for (int m = 0; m < 4; m++) {
            float4 h4 = *(const float4*)&h_lds[4 * pr + 512 * m];
            a0 += wreg[0][m].x * h4.x + wreg[0][m].y * h4.y + wreg[0][m].z * h4.z + wreg[0][m].w * h4.w;
            a1 += wreg[1][m].x * h4.x + wreg[1][m].y * h4.y + wreg[1][m].z * h4.z + wreg[1][m].w * h4.w;
            a2 += wreg[2][m].x * h4.x + wreg[2][m].y * h4.y + wreg[2][m].z * h4.z + wreg[2][m].w * h4.w;
        }
        #pragma unroll
        for (int s = 32; s >= 1; s >>= 1) {
            a0 += __shfl_xor(a0, s, 64);
            a1 += __shfl_xor(a1, s, 64);
            a2 += __shfl_xor(a2, s, 64);
        }
        if (lane == 0) { pg[w][0] = a0; pg[w][1] = a1; pg[w][2] = a2; }
        __syncthreads();

        // ---- combine + gates + publish (all in wave 0, lockstep) ----
        if (w == 0) {
            if (lane < 24) {
                const int kk = lane / 3, j = lane - 3 * kk;
                hg_lds[lane] = pg[2 * kk][j] + pg[2 * kk + 1][j];
            }
            asm volatile("s_waitcnt lgkmcnt(0)" ::: "memory");  // intra-wave LDS wr->rd
            float h_new = 0.f;
            if (lane < 8) {
                const float r = 1.f / (1.f + expf(-(ig0 + hg_lds[lane])));
                const float z = 1.f / (1.f + expf(-(ig1 + hg_lds[8 + lane])));
                const float n = tanhf(ig2 + r * (hg_lds[16 + lane] + bn));
                const float hp = h_lds[i];
                h_new = n + z * (hp - n);
                hs[(size_t)t * HID + i] = h_new;     // plain cached store
            }
            const float ha = __shfl(h_new, lane * 2, 64);
            const float hb = __shfl(h_new, lane * 2 + 1, 64);
            if (lane < 4) {
                cstore_f4(atoms + ((t + 1) & 1) * 1024 + b * 4 + lane,
                          ha, hb, (float)(base + t + 1), 0.f);
            }
        }
        // no end barrier: self-atom gating + top barrier provide ordering
    }
}

// ---------------------------------------------------------------------------
extern "C" void kernel_launch(void* const* d_in, const int* in_sizes, int n_in,
                              void* d_out, int out_size, void* d_ws, size_t ws_size,
                              hipStream_t stream) {
    const float* x     = (const float*)d_in[0];
    const float* enc_w = (const float*)d_in[1];
    const float* enc_b = (const float*)d_in[2];
    const float* w_ih  = (const float*)d_in[3];
    const float* w_hh  = (const float*)d_in[4];
    const float* b_ih  = (const float*)d_in[5];
    const float* b_n   = (const float*)d_in[6];
    const float* w0    = (const float*)d_in[7];
    const float* b0    = (const float*)d_in[8];
    const float* w1    = (const float*)d_in[9];
    const float* b1    = (const float*)d_in[10];
    const float* w2    = (const float*)d_in[11];
    const float* b2    = (const float*)d_in[12];
    float* out = (float*)d_out;

    // workspace (~136 MB): R1 64MB (ig chunk -> dec h1), R2 64MB (hs -> dec h2)
    float* R1    = (float*)d_ws;                          // 16,777,216 f
    float* R2    = R1 + (size_t)16777216;                 // 16,777,216 f
    float* wcomb = R2 + (size_t)16777216;                 // 393,216 f
    float* bcomb = wcomb + 393216;                        // 6,144 f
    float4* atoms = (float4*)(bcomb + 6144);              // 2*1024 float4 = 32KB

    (void)hipMemsetAsync(atoms, 0, 2 * 1024 * sizeof(float4), stream);

    // fold encoder into GRU input weights:
    //   W_comb = w_ih @ enc_w   [6144,64];  b_comb = w_ih @ enc_b + b_ih
    sgemm_nn<<<dim3(1, 96), 256, 0, stream>>>(w_ih, enc_w, wcomb, 6144, 64, 2048);
    bcomb_kernel<<<dim3(1536), 256, 0, stream>>>(w_ih, enc_b, b_ih, bcomb);

    // chunked: ig = x @ W_comb^T + b_comb (K=64), then sequential scan
    for (int c = 0; c < T_STEPS / CHUNK; c++) {
        sgemm_bias<0><<<dim3(H3 / 64, CHUNK / 64), 256, 0, stream>>>(
            x + (size_t)c * CHUNK * 64, wcomb, bcomb, R1, CHUNK, H3, 64);
        gru_scan<<<dim3(NBLK), dim3(1024), 0, stream>>>(
            w_hh, b_n, R1, R2 + (size_t)c * CHUNK * HID, atoms, c * CHUNK, CHUNK);
    }

    // decoder MLP (aliased: R2=hs -> R1=h1 -> R2=h2 -> out)
    sgemm_bias<1><<<dim3(HID / 64, T_STEPS / 64), 256, 0, stream>>>(
        R2, w0, b0, R1, T_STEPS, HID, HID);
    sgemm_bias<1><<<dim3(HID / 64, T_STEPS / 64), 256, 0, stream>>>(
        R1, w1, b1, R2, T_STEPS, HID, HID);
    sgemm_bias<0><<<dim3(1, T_STEPS / 64), 256, 0, stream>>>(
        R2, w2, b2, out, T_STEPS, 49, 2048);
}